// Round 10
// baseline (229.989 us; speedup 1.0000x reference)
//
#include <hip/hip_runtime.h>

#define HEADS 16
#define DHEAD 64
#define BATCH 2
#define SEQ   2048
#define DIM   1024
#define ROWS  (BATCH*SEQ)      // 4096
#define SCALE_LOG2E 0.180336880f   // 0.125 * log2(e)

typedef short v8s __attribute__((ext_vector_type(8)));
typedef float v4f __attribute__((ext_vector_type(4)));

__device__ __forceinline__ float fast_exp2(float x) {
    return __builtin_amdgcn_exp2f(x);   // v_exp_f32: D = 2^S0
}

__device__ __forceinline__ unsigned short f2bf(float f) {
    unsigned u = __float_as_uint(f);
    u += 0x7FFFu + ((u >> 16) & 1u);   // RNE
    return (unsigned short)(u >> 16);
}

__device__ __forceinline__ float bf2f(unsigned short u) {
    return __uint_as_float(((unsigned)u) << 16);
}

// pack two f32 -> bf16x2 dword (truncation): low short = bf(lo), high = bf(hi)
__device__ __forceinline__ unsigned pk_bf2(float hi, float lo) {
    return __builtin_amdgcn_perm(__float_as_uint(hi), __float_as_uint(lo), 0x07060302u);
}

// async global->LDS, 16B per lane (dest = wave-uniform base + lane*16)
#define GLDS16(g, l) __builtin_amdgcn_global_load_lds( \
    (__attribute__((address_space(1))) void*)(g), \
    (__attribute__((address_space(3))) void*)(l), 16, 0, 0)

// ---------------- Fused prep: LayerNorm (blocks 0..4095) + 3 transposes ----------
__global__ __launch_bounds__(256) void prep_kernel(const float* __restrict__ x,
                                                   const float* __restrict__ gamma,
                                                   const float* __restrict__ beta,
                                                   const float* __restrict__ Wqk,
                                                   const float* __restrict__ Wv,
                                                   const float* __restrict__ Wout,
                                                   unsigned short* __restrict__ xn,
                                                   unsigned short* __restrict__ Tqk,
                                                   unsigned short* __restrict__ Tv,
                                                   unsigned short* __restrict__ To) {
    __shared__ float tile[64][65];
    __shared__ float ss[4], ssq[4];
    int gid = blockIdx.x;
    int t = threadIdx.x;
    if (gid < ROWS) {
        // ---- LayerNorm row ----
        const float* xr = x + (size_t)gid * DIM;
        float4 v = *(const float4*)(xr + t * 4);
        float s  = v.x + v.y + v.z + v.w;
        float sq = v.x * v.x + v.y * v.y + v.z * v.z + v.w * v.w;
#pragma unroll
        for (int off = 32; off > 0; off >>= 1) {
            s  += __shfl_down(s,  off, 64);
            sq += __shfl_down(sq, off, 64);
        }
        int wave = t >> 6, lane = t & 63;
        if (lane == 0) { ss[wave] = s; ssq[wave] = sq; }
        __syncthreads();
        float tot  = ss[0] + ss[1] + ss[2] + ss[3];
        float totq = ssq[0] + ssq[1] + ssq[2] + ssq[3];
        float mean = tot * (1.f / DIM);
        float var  = totq * (1.f / DIM) - mean * mean;
        float rstd = rsqrtf(var + 1e-5f);
        float4 g = *(const float4*)(gamma + t * 4);
        float4 bb = *(const float4*)(beta + t * 4);
        ushort4 o;
        o.x = f2bf((v.x - mean) * rstd * g.x + bb.x);
        o.y = f2bf((v.y - mean) * rstd * g.y + bb.y);
        o.z = f2bf((v.z - mean) * rstd * g.z + bb.z);
        o.w = f2bf((v.w - mean) * rstd * g.w + bb.w);
        *(ushort4*)(xn + (size_t)gid * DIM + t * 4) = o;
        return;
    }
    // ---- transpose blocks ----
    int g2 = gid - ROWS;            // 0..1023
    const float* W; unsigned short* Wt; int Nw, n0, k0;
    if (g2 < 512)      { W = Wqk;  Wt = Tqk; Nw = 2048; n0 = (g2 & 31) * 64; k0 = (g2 >> 5) * 64; }
    else if (g2 < 768) { int g3 = g2 - 512; W = Wv;  Wt = Tv; Nw = 1024; n0 = (g3 & 15) * 64; k0 = (g3 >> 4) * 64; }
    else               { int g3 = g2 - 768; W = Wout; Wt = To; Nw = 1024; n0 = (g3 & 15) * 64; k0 = (g3 >> 4) * 64; }
#pragma unroll
    for (int l = 0; l < 4; ++l) {
        int kk = (t >> 4) + l * 16;
        int nn = (t & 15) * 4;
        float4 v = *(const float4*)(W + (size_t)(k0 + kk) * Nw + n0 + nn);
        tile[kk][nn + 0] = v.x; tile[kk][nn + 1] = v.y;
        tile[kk][nn + 2] = v.z; tile[kk][nn + 3] = v.w;
    }
    __syncthreads();
#pragma unroll
    for (int l = 0; l < 4; ++l) {
        int cid = t + l * 256;
        int nn = cid >> 4, kc = (cid & 15) * 4;
        ushort4 o;
        o.x = f2bf(tile[kc + 0][nn]);
        o.y = f2bf(tile[kc + 1][nn]);
        o.z = f2bf(tile[kc + 2][nn]);
        o.w = f2bf(tile[kc + 3][nn]);
        *(ushort4*)(Wt + (size_t)(n0 + nn) * DIM + k0 + kc) = o;
    }
}

// ---------------- MFMA GEMM core: fragment-ordered LDS, BK=64 ----------------
// LDS = slots of 1 KB (64 lanes x 16 B); slot (g,kk) holds rows g*16+l15,
// shorts kk*32+quad*8. GLDS16 dest is lane-linear; ds_read_b128 is lane-linear.
// Both conflict-free. BN=128: wave=64x64; BN=64: wave=32x64.
template<int BN, bool SWAP>
__device__ __forceinline__ void mm_core3(const unsigned short* __restrict__ A,
                                         const unsigned short* __restrict__ Bt,
                                         int K, int aTile, int bTile,
                                         unsigned short* As,   // 16 slots
                                         unsigned short* Bs,   // 16 or 8 slots
                                         v4f (*acc)[4]) {
    constexpr int MI = (BN == 128) ? 4 : 2;
    constexpr int BSLOT = (BN == 128) ? 4 : 2;
    int t = threadIdx.x;
    int w = t >> 6, L = t & 63, l15 = L & 15, quad = L >> 4;
    int aOffT = (BN == 128) ? (w >> 1) * 4 : w * 2;   // row-tile index of wave's rows
    int bOffT = 0;
    if (BN == 128) bOffT = (w & 1) * 4;
    for (int k0 = 0; k0 < K; k0 += 64) {
        __syncthreads();    // previous tile fully consumed
#pragma unroll
        for (int j = 0; j < 4; ++j) {
            int slot = w * 4 + j;
            int g = slot >> 1, kk = slot & 1;
            GLDS16(A + (size_t)(aTile + g * 16 + l15) * K + k0 + kk * 32 + quad * 8,
                   As + slot * 512);
        }
#pragma unroll
        for (int j = 0; j < BSLOT; ++j) {
            int slot = w * BSLOT + j;
            int g = slot >> 1, kk = slot & 1;
            GLDS16(Bt + (size_t)(bTile + g * 16 + l15) * K + k0 + kk * 32 + quad * 8,
                   Bs + slot * 512);
        }
        __syncthreads();    // drains vmcnt: staged tile visible
#pragma unroll
        for (int kk = 0; kk < 2; ++kk) {
            v8s a[MI], b[4];
#pragma unroll
            for (int i = 0; i < MI; ++i)
                a[i] = *(const v8s*)(As + ((aOffT + i) * 2 + kk) * 512 + L * 8);
#pragma unroll
            for (int j = 0; j < 4; ++j)
                b[j] = *(const v8s*)(Bs + ((bOffT + j) * 2 + kk) * 512 + L * 8);
#pragma unroll
            for (int i = 0; i < MI; ++i)
#pragma unroll
                for (int j = 0; j < 4; ++j)
                    acc[i][j] = SWAP
                        ? __builtin_amdgcn_mfma_f32_16x16x32_bf16(b[j], a[i], acc[i][j], 0, 0, 0)
                        : __builtin_amdgcn_mfma_f32_16x16x32_bf16(a[i], b[j], acc[i][j], 0, 0, 0);
        }
    }
}

// ---------------- Fused GEMM -> q_h/k_h [b][h][seq][64] + v_t [b][h][64][seq] ----
__global__ __launch_bounds__(256) void gemm_qkv_kernel(const unsigned short* __restrict__ A,
                                                       const unsigned short* __restrict__ Bt,
                                                       unsigned short* __restrict__ q_h,
                                                       unsigned short* __restrict__ k_h,
                                                       unsigned short* __restrict__ v_t) {
    __shared__ __align__(16) unsigned short As[16 * 512];   // 16 KB
    __shared__ __align__(16) unsigned short Bs[16 * 512];   // 16 KB
    int t = threadIdx.x, w = t >> 6, L = t & 63, l15 = L & 15, quad = L >> 4;
    int aTile = blockIdx.y * 128, bTile = blockIdx.x * 128;
    int aOff = (w >> 1) * 64, bOff = (w & 1) * 64;
    v4f acc[4][4] = {};
    if (bTile < 2048) {
        mm_core3<128, true>(A, Bt, DIM, aTile, bTile, As, Bs, acc);
#pragma unroll
        for (int j = 0; j < 4; ++j) {
            int col = bTile + bOff + j * 16 + quad * 4;   // 4 consecutive
            unsigned short* dst = (col < 1024) ? q_h : k_h;
            int c = col & 1023;
            int h = c >> 6, d = c & 63;
#pragma unroll
            for (int i = 0; i < 4; ++i) {
                int m = aTile + aOff + i * 16 + l15;
                int b = m >> 11, seq = m & 2047;
                ushort4 o;
                o.x = f2bf(acc[i][j][0]); o.y = f2bf(acc[i][j][1]);
                o.z = f2bf(acc[i][j][2]); o.w = f2bf(acc[i][j][3]);
                *(ushort4*)(dst + (((size_t)(b * 16 + h)) * SEQ + seq) * 64 + d) = o;
            }
        }
    } else {
        mm_core3<128, false>(A, Bt, DIM, aTile, bTile, As, Bs, acc);
#pragma unroll
        for (int j = 0; j < 4; ++j) {
            int c = bTile + bOff + j * 16 + l15 - 2048;
            int h = c >> 6, d = c & 63;
#pragma unroll
            for (int i = 0; i < 4; ++i) {
                int m0 = aTile + aOff + i * 16 + quad * 4;
                int b = m0 >> 11, seq0 = m0 & 2047;
                ushort4 o;
                o.x = f2bf(acc[i][j][0]); o.y = f2bf(acc[i][j][1]);
                o.z = f2bf(acc[i][j][2]); o.w = f2bf(acc[i][j][3]);
                *(ushort4*)(v_t + (((size_t)(b * 16 + h)) * 64 + d) * SEQ + seq0) = o;
            }
        }
    }
}

// ---------------- Final GEMM + bias, f32 out (BN=64, C^T -> float4 stores) ------
__global__ __launch_bounds__(256) void gemm_out_kernel(const unsigned short* __restrict__ A,
                                                       const unsigned short* __restrict__ Bt,
                                                       const float* __restrict__ bias,
                                                       float* __restrict__ C) {
    __shared__ __align__(16) unsigned short As[16 * 512];   // 16 KB
    __shared__ __align__(16) unsigned short Bs[8 * 512];    // 8 KB
    int t = threadIdx.x, w = t >> 6, L = t & 63, l15 = L & 15, quad = L >> 4;
    int aTile = blockIdx.y * 128, bTile = blockIdx.x * 64;
    v4f acc[2][4] = {};
    mm_core3<64, true>(A, Bt, DIM, aTile, bTile, As, Bs, acc);
#pragma unroll
    for (int j = 0; j < 4; ++j) {
        int n = bTile + j * 16 + quad * 4;    // 4 consecutive cols
        float4 bv = *(const float4*)(bias + n);
#pragma unroll
        for (int i = 0; i < 2; ++i) {
            int m = aTile + w * 32 + i * 16 + l15;
            float4 o = make_float4(acc[i][j][0] + bv.x, acc[i][j][1] + bv.y,
                                   acc[i][j][2] + bv.z, acc[i][j][3] + bv.w);
            *(float4*)(C + (size_t)m * DIM + n) = o;
        }
    }
}

// ---------------- MFMA flash attention, split-K2 (no online softmax) ----------
// grid.x = 32: qt = bx>>1, key-half kh = bx&1 -> 1024 blocks = 4 blocks/CU.
// Each block: 128 Q rows x 1024 keys; partial O (bf16) and l (f32) out.
__global__ __launch_bounds__(256) void attn_kernel(const unsigned short* __restrict__ q_h,
                                                   const unsigned short* __restrict__ k_h,
                                                   const unsigned short* __restrict__ v_t,
                                                   unsigned short* __restrict__ opart,
                                                   float* __restrict__ lpart) {
    __shared__ __align__(16) unsigned short KF[8 * 64 * 8];     // 8 KB
    __shared__ __align__(16) unsigned short VF[8 * 64 * 8];     // 8 KB
    __shared__ __align__(16) unsigned short Pld[4][2][16 * 72]; // 18 KB
    int qt = blockIdx.x >> 1, kh = blockIdx.x & 1;
    int h = blockIdx.y, b = blockIdx.z;
    int bh = b * HEADS + h;
    int w = threadIdx.x >> 6;
    int L = threadIdx.x & 63, l15 = L & 15, quad = L >> 4;

    const unsigned short* qp = q_h + ((size_t)bh * SEQ + qt * 128 + w * 32 + l15) * 64 + quad * 8;
    v8s qf[2][2];
    qf[0][0] = *(const v8s*)(qp);
    qf[0][1] = *(const v8s*)(qp + 32);
    qf[1][0] = *(const v8s*)(qp + 16 * 64);
    qf[1][1] = *(const v8s*)(qp + 16 * 64 + 32);

    const unsigned short* kstage = k_h + ((size_t)bh * SEQ + w * 16 + l15) * 64 + quad * 8;
    const unsigned short* vstage = v_t + ((size_t)bh * 64 + w * 16 + l15) * SEQ + quad * 8;

    v4f o[2][4] = {};
    v4f lacc[2] = {};
    const short ob = (short)0x3F80;   // bf16 1.0
    const v8s ones = {ob, ob, ob, ob, ob, ob, ob, ob};

    int jbase = kh * 1024;
    v8s ks0 = *(const v8s*)(kstage + (size_t)jbase * 64);
    v8s ks1 = *(const v8s*)(kstage + (size_t)jbase * 64 + 32);
    v8s vs0 = *(const v8s*)(vstage + jbase);
    v8s vs1 = *(const v8s*)(vstage + jbase + 32);

    for (int jj = 0; jj < 1024; jj += 64) {
        int j0 = jbase + jj;
        __syncthreads();
        *(v8s*)&KF[((w * 2 + 0) * 64 + L) * 8] = ks0;
        *(v8s*)&KF[((w * 2 + 1) * 64 + L) * 8] = ks1;
        *(v8s*)&VF[((w * 2 + 0) * 64 + L) * 8] = vs0;
        *(v8s*)&VF[((w * 2 + 1) * 64 + L) * 8] = vs1;
        __syncthreads();
        if (jj + 64 < 1024) {
            ks0 = *(const v8s*)(kstage + (size_t)(j0 + 64) * 64);
            ks1 = *(const v8s*)(kstage + (size_t)(j0 + 64) * 64 + 32);
            vs0 = *(const v8s*)(vstage + j0 + 64);
            vs1 = *(const v8s*)(vstage + j0 + 64 + 32);
        }
        v8s kf[4][2], vf[4][2];
#pragma unroll
        for (int jt = 0; jt < 4; ++jt) {
            kf[jt][0] = *(const v8s*)&KF[((jt * 2 + 0) * 64 + L) * 8];
            kf[jt][1] = *(const v8s*)&KF[((jt * 2 + 1) * 64 + L) * 8];
            vf[jt][0] = *(const v8s*)&VF[((jt * 2 + 0) * 64 + L) * 8];
            vf[jt][1] = *(const v8s*)&VF[((jt * 2 + 1) * 64 + L) * 8];
        }
        v4f s[2][4] = {};
#pragma unroll
        for (int m = 0; m < 2; ++m)
#pragma unroll
            for (int jt = 0; jt < 4; ++jt) {
                s[m][jt] = __builtin_amdgcn_mfma_f32_16x16x32_bf16(kf[jt][0], qf[m][0], s[m][jt], 0, 0, 0);
                s[m][jt] = __builtin_amdgcn_mfma_f32_16x16x32_bf16(kf[jt][1], qf[m][1], s[m][jt], 0, 0, 0);
            }
#pragma unroll
        for (int m = 0; m < 2; ++m)
#pragma unroll
            for (int jt = 0; jt < 4; ++jt) {
                float p0 = fast_exp2(s[m][jt][0] * SCALE_LOG2E);
                float p1 = fast_exp2(s[m][jt][1] * SCALE_LOG2E);
                float p2 = fast_exp2(s[m][jt][2] * SCALE_LOG2E);
                float p3 = fast_exp2(s[m][jt][3] * SCALE_LOG2E);
                uint2 pk;
                pk.x = pk_bf2(p1, p0);
                pk.y = pk_bf2(p3, p2);
                *(uint2*)&Pld[w][m][l15 * 72 + jt * 16 + quad * 4] = pk;
            }
#pragma unroll
        for (int m = 0; m < 2; ++m) {
            v8s pb0 = *(const v8s*)&Pld[w][m][l15 * 72 + quad * 8];
            v8s pb1 = *(const v8s*)&Pld[w][m][l15 * 72 + 32 + quad * 8];
#pragma unroll
            for (int dt = 0; dt < 4; ++dt) {
                o[m][dt] = __builtin_amdgcn_mfma_f32_16x16x32_bf16(vf[dt][0], pb0, o[m][dt], 0, 0, 0);
                o[m][dt] = __builtin_amdgcn_mfma_f32_16x16x32_bf16(vf[dt][1], pb1, o[m][dt], 0, 0, 0);
            }
            lacc[m] = __builtin_amdgcn_mfma_f32_16x16x32_bf16(ones, pb0, lacc[m], 0, 0, 0);
            lacc[m] = __builtin_amdgcn_mfma_f32_16x16x32_bf16(ones, pb1, lacc[m], 0, 0, 0);
        }
    }
    // partial stores (no normalization here)
#pragma unroll
    for (int m = 0; m < 2; ++m) {
        int seq = qt * 128 + w * 32 + m * 16 + l15;
        int rowg = b * SEQ + seq;
        if (quad == 0)
            lpart[((size_t)(kh * 32 + bh)) * SEQ + seq] = lacc[m][0];
#pragma unroll
        for (int dt = 0; dt < 4; ++dt) {
            uint2 ov;
            ov.x = pk_bf2(o[m][dt][1], o[m][dt][0]);
            ov.y = pk_bf2(o[m][dt][3], o[m][dt][2]);
            *(uint2*)(opart + ((size_t)kh * ROWS + rowg) * DIM + h * 64 + dt * 16 + quad * 4) = ov;
        }
    }
}

// ---------------- Combine: ao = (O0 + O1) / (l0 + l1), bf16 out ----------------
__global__ __launch_bounds__(256) void combine_kernel(const unsigned short* __restrict__ opart,
                                                      const float* __restrict__ lpart,
                                                      unsigned short* __restrict__ ao) {
    int rowg = blockIdx.x, t = threadIdx.x;
    int b = rowg >> 11, seq = rowg & 2047;
    int h = t >> 4;                    // (t*4)>>6
    int bh = b * 16 + h;
    float l0 = lpart[(size_t)bh * SEQ + seq];
    float l1 = lpart[((size_t)(32 + bh)) * SEQ + seq];
    float inv = 1.f / (l0 + l1);
    size_t base = (size_t)rowg * DIM + t * 4;
    ushort4 a0 = *(const ushort4*)(opart + base);
    ushort4 a1 = *(const ushort4*)(opart + (size_t)ROWS * DIM + base);
    ushort4 o;
    o.x = f2bf((bf2f(a0.x) + bf2f(a1.x)) * inv);
    o.y = f2bf((bf2f(a0.y) + bf2f(a1.y)) * inv);
    o.z = f2bf((bf2f(a0.z) + bf2f(a1.z)) * inv);
    o.w = f2bf((bf2f(a0.w) + bf2f(a1.w)) * inv);
    *(ushort4*)(ao + base) = o;
}

extern "C" void kernel_launch(void* const* d_in, const int* in_sizes, int n_in,
                              void* d_out, int out_size, void* d_ws, size_t ws_size,
                              hipStream_t stream) {
    const float* x     = (const float*)d_in[0];
    const float* gamma = (const float*)d_in[1];
    const float* beta  = (const float*)d_in[2];
    const float* Wqk   = (const float*)d_in[3];
    const float* Wv    = (const float*)d_in[4];
    const float* Wout  = (const float*)d_in[5];
    const float* bout  = (const float*)d_in[6];
    float* out = (float*)d_out;

    unsigned short* ws = (unsigned short*)d_ws;
    unsigned short* xn    = ws;                            // 4096*1024      (8 MB)
    unsigned short* Wt_qk = xn + (size_t)ROWS * DIM;       // 2048*1024      (4 MB)
    unsigned short* Wt_v  = Wt_qk + (size_t)2048 * DIM;    // 1024*1024      (2 MB, contiguous after qk)
    unsigned short* Wt_o  = Wt_v + (size_t)DIM * DIM;      // 1024*1024      (2 MB)
    unsigned short* q_h   = Wt_o + (size_t)DIM * DIM;      // 4096*1024      (8 MB)
    unsigned short* k_h   = q_h + (size_t)ROWS * DIM;      // 4096*1024      (8 MB)
    unsigned short* v_t   = k_h + (size_t)ROWS * DIM;      // 4096*1024      (8 MB)
    unsigned short* ao    = v_t + (size_t)ROWS * DIM;      // 4096*1024      (8 MB)
    unsigned short* opart = ao + (size_t)ROWS * DIM;       // 2*4096*1024    (16 MB)
    float*          lpart = (float*)(opart + (size_t)2 * ROWS * DIM);  // 2*32*2048 f32 (0.5 MB)

    prep_kernel<<<ROWS + 1024, 256, 0, stream>>>(x, gamma, beta, Wqk, Wv, Wout,
                                                 xn, Wt_qk, Wt_v, Wt_o);
    gemm_qkv_kernel<<<dim3(3072 / 128, ROWS / 128), 256, 0, stream>>>(xn, Wt_qk, q_h, k_h, v_t);
    attn_kernel<<<dim3(2 * SEQ / 128, HEADS, BATCH), 256, 0, stream>>>(q_h, k_h, v_t, opart, lpart);
    combine_kernel<<<ROWS, 256, 0, stream>>>(opart, lpart, ao);
    gemm_out_kernel<<<dim3(DIM / 64, ROWS / 128), 256, 0, stream>>>(ao, Wt_o, bout, out);
}

// Round 12
// 219.540 us; speedup vs baseline: 1.0476x; 1.0476x over previous
//
#include <hip/hip_runtime.h>

#define HEADS 16
#define DHEAD 64
#define BATCH 2
#define SEQ   2048
#define DIM   1024
#define ROWS  (BATCH*SEQ)      // 4096
#define SCALE_LOG2E 0.180336880f   // 0.125 * log2(e)

typedef short v8s __attribute__((ext_vector_type(8)));
typedef float v4f __attribute__((ext_vector_type(4)));

__device__ __forceinline__ float fast_exp2(float x) {
    return __builtin_amdgcn_exp2f(x);   // v_exp_f32: D = 2^S0
}

__device__ __forceinline__ unsigned short f2bf(float f) {
    unsigned u = __float_as_uint(f);
    u += 0x7FFFu + ((u >> 16) & 1u);   // RNE
    return (unsigned short)(u >> 16);
}

__device__ __forceinline__ float bf2f(unsigned short u) {
    return __uint_as_float(((unsigned)u) << 16);
}

// pack two f32 -> bf16x2 dword (truncation): low short = bf(lo), high = bf(hi)
__device__ __forceinline__ unsigned pk_bf2(float hi, float lo) {
    return __builtin_amdgcn_perm(__float_as_uint(hi), __float_as_uint(lo), 0x07060302u);
}

// async global->LDS, 16B per lane (dest = wave-uniform base + lane*16)
#define GLDS16(g, l) __builtin_amdgcn_global_load_lds( \
    (__attribute__((address_space(1))) void*)(g), \
    (__attribute__((address_space(3))) void*)(l), 16, 0, 0)

// ---------------- LayerNorm: one block per row, bf16 out ----------------
__global__ __launch_bounds__(256) void ln_kernel(const float* __restrict__ x,
                                                 const float* __restrict__ gamma,
                                                 const float* __restrict__ beta,
                                                 unsigned short* __restrict__ xn) {
    int row = blockIdx.x;
    const float* xr = x + (size_t)row * DIM;
    int t = threadIdx.x;
    float4 v = *(const float4*)(xr + t * 4);
    float s  = v.x + v.y + v.z + v.w;
    float sq = v.x * v.x + v.y * v.y + v.z * v.z + v.w * v.w;
#pragma unroll
    for (int off = 32; off > 0; off >>= 1) {
        s  += __shfl_down(s,  off, 64);
        sq += __shfl_down(sq, off, 64);
    }
    __shared__ float ss[4], ssq[4];
    int wave = t >> 6, lane = t & 63;
    if (lane == 0) { ss[wave] = s; ssq[wave] = sq; }
    __syncthreads();
    float tot  = ss[0] + ss[1] + ss[2] + ss[3];
    float totq = ssq[0] + ssq[1] + ssq[2] + ssq[3];
    float mean = tot * (1.f / DIM);
    float var  = totq * (1.f / DIM) - mean * mean;
    float rstd = rsqrtf(var + 1e-5f);
    float4 g = *(const float4*)(gamma + t * 4);
    float4 bb = *(const float4*)(beta + t * 4);
    ushort4 o;
    o.x = f2bf((v.x - mean) * rstd * g.x + bb.x);
    o.y = f2bf((v.y - mean) * rstd * g.y + bb.y);
    o.z = f2bf((v.z - mean) * rstd * g.z + bb.z);
    o.w = f2bf((v.w - mean) * rstd * g.w + bb.w);
    *(ushort4*)(xn + (size_t)row * DIM + t * 4) = o;
}

// ---------------- Fused transpose + f32->bf16 for all 3 weights ----------------
__global__ __launch_bounds__(256) void tr_all_kernel(const float* __restrict__ Wqk,
                                                     const float* __restrict__ Wv,
                                                     const float* __restrict__ Wout,
                                                     unsigned short* __restrict__ Tqk,
                                                     unsigned short* __restrict__ Tv,
                                                     unsigned short* __restrict__ To) {
    int z = blockIdx.z;
    const float* W = (z == 0) ? Wqk : (z == 1) ? Wv : Wout;
    unsigned short* Wt = (z == 0) ? Tqk : (z == 1) ? Tv : To;
    int Nw = (z == 0) ? 2048 : 1024;
    int n0 = blockIdx.x * 64, k0 = blockIdx.y * 64;
    if (n0 >= Nw) return;
    __shared__ float tile[64][65];
    int tid = threadIdx.x;
#pragma unroll
    for (int l = 0; l < 4; ++l) {
        int kk = (tid >> 4) + l * 16;
        int nn = (tid & 15) * 4;
        float4 v = *(const float4*)(W + (size_t)(k0 + kk) * Nw + n0 + nn);
        tile[kk][nn + 0] = v.x; tile[kk][nn + 1] = v.y;
        tile[kk][nn + 2] = v.z; tile[kk][nn + 3] = v.w;
    }
    __syncthreads();
#pragma unroll
    for (int l = 0; l < 4; ++l) {
        int cid = tid + l * 256;
        int nn = cid >> 4, kc = (cid & 15) * 4;
        ushort4 o;
        o.x = f2bf(tile[kc + 0][nn]);
        o.y = f2bf(tile[kc + 1][nn]);
        o.z = f2bf(tile[kc + 2][nn]);
        o.w = f2bf(tile[kc + 3][nn]);
        *(ushort4*)(Wt + (size_t)(n0 + nn) * DIM + k0 + kc) = o;
    }
}

// ---------------- MFMA GEMM core: BK=32, fragment-ordered slots ----------------
// Slot = 1 KB = 16 rows x 32 shorts; lane L holds (row l15, shorts quad*8..+7).
// GLDS16 dest lane-linear; ds_read_b128 lane-linear: both conflict-free.
template<int BN, bool SWAP>
__device__ __forceinline__ void mm_core4(const unsigned short* __restrict__ A,
                                         const unsigned short* __restrict__ Bt,
                                         int K, int aTile, int bTile,
                                         unsigned short* As,   // 8 slots
                                         unsigned short* Bs,   // 8 or 4 slots
                                         v4f (*acc)[4]) {
    constexpr int MI = (BN == 128) ? 4 : 2;
    int t = threadIdx.x;
    int w = t >> 6, L = t & 63, l15 = L & 15, quad = L >> 4;
    int aSlot0 = (BN == 128) ? (w >> 1) * 4 : w * 2;
    int bSlot0 = (BN == 128) ? (w & 1) * 4 : 0;
    for (int k0 = 0; k0 < K; k0 += 32) {
        __syncthreads();    // previous tile fully consumed
#pragma unroll
        for (int j = 0; j < 2; ++j) {
            int slot = w * 2 + j;
            GLDS16(A + (size_t)(aTile + slot * 16 + l15) * K + k0 + quad * 8,
                   As + slot * 512);
        }
        if (BN == 128) {
#pragma unroll
            for (int j = 0; j < 2; ++j) {
                int slot = w * 2 + j;
                GLDS16(Bt + (size_t)(bTile + slot * 16 + l15) * K + k0 + quad * 8,
                       Bs + slot * 512);
            }
        } else {
            GLDS16(Bt + (size_t)(bTile + w * 16 + l15) * K + k0 + quad * 8,
                   Bs + w * 512);
        }
        __syncthreads();    // drains vmcnt: staged tile visible
        v8s a[MI], b[4];
#pragma unroll
        for (int i = 0; i < MI; ++i) a[i] = *(const v8s*)(As + (aSlot0 + i) * 512 + L * 8);
#pragma unroll
        for (int j = 0; j < 4; ++j) b[j] = *(const v8s*)(Bs + (bSlot0 + j) * 512 + L * 8);
#pragma unroll
        for (int i = 0; i < MI; ++i)
#pragma unroll
            for (int j = 0; j < 4; ++j)
                acc[i][j] = SWAP
                    ? __builtin_amdgcn_mfma_f32_16x16x32_bf16(b[j], a[i], acc[i][j], 0, 0, 0)
                    : __builtin_amdgcn_mfma_f32_16x16x32_bf16(a[i], b[j], acc[i][j], 0, 0, 0);
    }
}

// ---------------- Fused GEMM -> q_h/k_h [bh][seq][64] + v_t [bh][64][seq] ------
// Epilogue: wave-private LDS round-trip (64x72-short tile) -> dense stores.
__global__ __launch_bounds__(256) void gemm_qkv_kernel(const unsigned short* __restrict__ A,
                                                       const unsigned short* __restrict__ Bt,
                                                       unsigned short* __restrict__ q_h,
                                                       unsigned short* __restrict__ k_h,
                                                       unsigned short* __restrict__ v_t) {
    __shared__ __align__(16) unsigned short buf[4 * 64 * 72];   // 36864 B
    unsigned short* As = buf;             // 8 slots = 4096 shorts
    unsigned short* Bs = buf + 4096;      // 8 slots
    int t = threadIdx.x, w = t >> 6, L = t & 63, l15 = L & 15, quad = L >> 4;
    int aTile = blockIdx.y * 128, bTile = blockIdx.x * 128;
    int aOff = (w >> 1) * 64, bOff = (w & 1) * 64;
    unsigned short* ct = buf + w * 4608;  // wave-private 64x72
    v4f acc[4][4] = {};
    if (bTile < 2048) {
        mm_core4<128, true>(A, Bt, DIM, aTile, bTile, As, Bs, acc);
        __syncthreads();   // staging buffers now reusable as ct
        // C^T: lane m = l15, 4 consecutive n (quad*4+r). LDS tile[m][n], stride 72.
#pragma unroll
        for (int i = 0; i < 4; ++i)
#pragma unroll
            for (int j = 0; j < 4; ++j) {
                uint2 pk;
                pk.x = pk_bf2(acc[i][j][1], acc[i][j][0]);
                pk.y = pk_bf2(acc[i][j][3], acc[i][j][2]);
                *(uint2*)&ct[(i * 16 + l15) * 72 + j * 16 + quad * 4] = pk;
            }
        int c0 = bTile + bOff;
        unsigned short* dst = (c0 < 1024) ? q_h : k_h;
        int h = (c0 & 1023) >> 6;
        int m0 = aTile + aOff;
        int b = m0 >> 11, seq0 = m0 & 2047;
        unsigned short* base = dst + (((size_t)(b * 16 + h)) * SEQ + seq0) * 64;
#pragma unroll
        for (int i2 = 0; i2 < 8; ++i2) {
            int row = i2 * 8 + (L >> 3);          // local m (seq)
            v8s vv = *(const v8s*)&ct[row * 72 + (L & 7) * 8];
            // offset = row*64 + d = i2*512 + L*8  -> dense 1KB per instruction
            *(v8s*)(base + (size_t)i2 * 512 + L * 8) = vv;
        }
    } else {
        mm_core4<128, false>(A, Bt, DIM, aTile, bTile, As, Bs, acc);
        __syncthreads();
        // C: lane n(d) = l15, 4 consecutive m (seq). LDS tile[d][seq], stride 72.
#pragma unroll
        for (int i = 0; i < 4; ++i)
#pragma unroll
            for (int j = 0; j < 4; ++j) {
                uint2 pk;
                pk.x = pk_bf2(acc[i][j][1], acc[i][j][0]);
                pk.y = pk_bf2(acc[i][j][3], acc[i][j][2]);
                *(uint2*)&ct[(j * 16 + l15) * 72 + i * 16 + quad * 4] = pk;
            }
        int c0 = bTile + bOff - 2048;
        int h = c0 >> 6;
        int m0 = aTile + aOff;
        int b = m0 >> 11, seq0 = m0 & 2047;
        unsigned short* base = v_t + (((size_t)(b * 16 + h)) * 64) * SEQ + seq0;
#pragma unroll
        for (int i2 = 0; i2 < 8; ++i2) {
            int d = i2 * 8 + (L >> 3);
            v8s vv = *(const v8s*)&ct[d * 72 + (L & 7) * 8];
            *(v8s*)(base + (size_t)d * SEQ + (L & 7) * 8) = vv;  // 8x128B segs/inst
        }
    }
}

// ---------------- Final GEMM + bias, f32 out (BN=64, C^T float4 stores) --------
__global__ __launch_bounds__(256) void gemm_out_kernel(const unsigned short* __restrict__ A,
                                                       const unsigned short* __restrict__ Bt,
                                                       const float* __restrict__ bias,
                                                       float* __restrict__ C) {
    __shared__ __align__(16) unsigned short As[8 * 512];   // 8 KB
    __shared__ __align__(16) unsigned short Bs[4 * 512];   // 4 KB
    int t = threadIdx.x, w = t >> 6, L = t & 63, l15 = L & 15, quad = L >> 4;
    int aTile = blockIdx.y * 128, bTile = blockIdx.x * 64;
    v4f acc[2][4] = {};
    mm_core4<64, true>(A, Bt, DIM, aTile, bTile, As, Bs, acc);
#pragma unroll
    for (int j = 0; j < 4; ++j) {
        int n = bTile + j * 16 + quad * 4;    // 4 consecutive cols
        float4 bv = *(const float4*)(bias + n);
#pragma unroll
        for (int i = 0; i < 2; ++i) {
            int m = aTile + w * 32 + i * 16 + l15;
            float4 o = make_float4(acc[i][j][0] + bv.x, acc[i][j][1] + bv.y,
                                   acc[i][j][2] + bv.z, acc[i][j][3] + bv.w);
            *(float4*)(C + (size_t)m * DIM + n) = o;
        }
    }
}

// ---------------- MFMA flash attention, split-K2 (no online softmax) ----------
__global__ __launch_bounds__(256) void attn_kernel(const unsigned short* __restrict__ q_h,
                                                   const unsigned short* __restrict__ k_h,
                                                   const unsigned short* __restrict__ v_t,
                                                   unsigned short* __restrict__ opart,
                                                   float* __restrict__ lpart) {
    __shared__ __align__(16) unsigned short KF[8 * 64 * 8];     // 8 KB
    __shared__ __align__(16) unsigned short VF[8 * 64 * 8];     // 8 KB
    __shared__ __align__(16) unsigned short Pld[4][2][16 * 72]; // 18 KB
    int qt = blockIdx.x >> 1, kh = blockIdx.x & 1;
    int h = blockIdx.y, b = blockIdx.z;
    int bh = b * HEADS + h;
    int w = threadIdx.x >> 6;
    int L = threadIdx.x & 63, l15 = L & 15, quad = L >> 4;

    const unsigned short* qp = q_h + ((size_t)bh * SEQ + qt * 128 + w * 32 + l15) * 64 + quad * 8;
    v8s qf[2][2];
    qf[0][0] = *(const v8s*)(qp);
    qf[0][1] = *(const v8s*)(qp + 32);
    qf[1][0] = *(const v8s*)(qp + 16 * 64);
    qf[1][1] = *(const v8s*)(qp + 16 * 64 + 32);

    const unsigned short* kstage = k_h + ((size_t)bh * SEQ + w * 16 + l15) * 64 + quad * 8;
    const unsigned short* vstage = v_t + ((size_t)bh * 64 + w * 16 + l15) * SEQ + quad * 8;

    v4f o[2][4] = {};
    v4f lacc[2] = {};
    const short ob = (short)0x3F80;   // bf16 1.0
    const v8s ones = {ob, ob, ob, ob, ob, ob, ob, ob};

    int jbase = kh * 1024;
    v8s ks0 = *(const v8s*)(kstage + (size_t)jbase * 64);
    v8s ks1 = *(const v8s*)(kstage + (size_t)jbase * 64 + 32);
    v8s vs0 = *(const v8s*)(vstage + jbase);
    v8s vs1 = *(const v8s*)(vstage + jbase + 32);

    for (int jj = 0; jj < 1024; jj += 64) {
        int j0 = jbase + jj;
        __syncthreads();
        *(v8s*)&KF[((w * 2 + 0) * 64 + L) * 8] = ks0;
        *(v8s*)&KF[((w * 2 + 1) * 64 + L) * 8] = ks1;
        *(v8s*)&VF[((w * 2 + 0) * 64 + L) * 8] = vs0;
        *(v8s*)&VF[((w * 2 + 1) * 64 + L) * 8] = vs1;
        __syncthreads();
        if (jj + 64 < 1024) {
            ks0 = *(const v8s*)(kstage + (size_t)(j0 + 64) * 64);
            ks1 = *(const v8s*)(kstage + (size_t)(j0 + 64) * 64 + 32);
            vs0 = *(const v8s*)(vstage + j0 + 64);
            vs1 = *(const v8s*)(vstage + j0 + 64 + 32);
        }
        v8s kf[4][2], vf[4][2];
#pragma unroll
        for (int jt = 0; jt < 4; ++jt) {
            kf[jt][0] = *(const v8s*)&KF[((jt * 2 + 0) * 64 + L) * 8];
            kf[jt][1] = *(const v8s*)&KF[((jt * 2 + 1) * 64 + L) * 8];
            vf[jt][0] = *(const v8s*)&VF[((jt * 2 + 0) * 64 + L) * 8];
            vf[jt][1] = *(const v8s*)&VF[((jt * 2 + 1) * 64 + L) * 8];
        }
        v4f s[2][4] = {};
#pragma unroll
        for (int m = 0; m < 2; ++m)
#pragma unroll
            for (int jt = 0; jt < 4; ++jt) {
                s[m][jt] = __builtin_amdgcn_mfma_f32_16x16x32_bf16(kf[jt][0], qf[m][0], s[m][jt], 0, 0, 0);
                s[m][jt] = __builtin_amdgcn_mfma_f32_16x16x32_bf16(kf[jt][1], qf[m][1], s[m][jt], 0, 0, 0);
            }
#pragma unroll
        for (int m = 0; m < 2; ++m)
#pragma unroll
            for (int jt = 0; jt < 4; ++jt) {
                float p0 = fast_exp2(s[m][jt][0] * SCALE_LOG2E);
                float p1 = fast_exp2(s[m][jt][1] * SCALE_LOG2E);
                float p2 = fast_exp2(s[m][jt][2] * SCALE_LOG2E);
                float p3 = fast_exp2(s[m][jt][3] * SCALE_LOG2E);
                uint2 pk;
                pk.x = pk_bf2(p1, p0);
                pk.y = pk_bf2(p3, p2);
                *(uint2*)&Pld[w][m][l15 * 72 + jt * 16 + quad * 4] = pk;
            }
#pragma unroll
        for (int m = 0; m < 2; ++m) {
            v8s pb0 = *(const v8s*)&Pld[w][m][l15 * 72 + quad * 8];
            v8s pb1 = *(const v8s*)&Pld[w][m][l15 * 72 + 32 + quad * 8];
#pragma unroll
            for (int dt = 0; dt < 4; ++dt) {
                o[m][dt] = __builtin_amdgcn_mfma_f32_16x16x32_bf16(vf[dt][0], pb0, o[m][dt], 0, 0, 0);
                o[m][dt] = __builtin_amdgcn_mfma_f32_16x16x32_bf16(vf[dt][1], pb1, o[m][dt], 0, 0, 0);
            }
            lacc[m] = __builtin_amdgcn_mfma_f32_16x16x32_bf16(ones, pb0, lacc[m], 0, 0, 0);
            lacc[m] = __builtin_amdgcn_mfma_f32_16x16x32_bf16(ones, pb1, lacc[m], 0, 0, 0);
        }
    }
#pragma unroll
    for (int m = 0; m < 2; ++m) {
        int seq = qt * 128 + w * 32 + m * 16 + l15;
        int rowg = b * SEQ + seq;
        if (quad == 0)
            lpart[((size_t)(kh * 32 + bh)) * SEQ + seq] = lacc[m][0];
#pragma unroll
        for (int dt = 0; dt < 4; ++dt) {
            uint2 ov;
            ov.x = pk_bf2(o[m][dt][1], o[m][dt][0]);
            ov.y = pk_bf2(o[m][dt][3], o[m][dt][2]);
            *(uint2*)(opart + ((size_t)kh * ROWS + rowg) * DIM + h * 64 + dt * 16 + quad * 4) = ov;
        }
    }
}

// ---------------- Combine: ao = (O0 + O1) / (l0 + l1), bf16 out ----------------
__global__ __launch_bounds__(256) void combine_kernel(const unsigned short* __restrict__ opart,
                                                      const float* __restrict__ lpart,
                                                      unsigned short* __restrict__ ao) {
    int rowg = blockIdx.x, t = threadIdx.x;
    int b = rowg >> 11, seq = rowg & 2047;
    int h = t >> 4;                    // (t*4)>>6
    int bh = b * 16 + h;
    float l0 = lpart[(size_t)bh * SEQ + seq];
    float l1 = lpart[((size_t)(32 + bh)) * SEQ + seq];
    float inv = 1.f / (l0 + l1);
    size_t base = (size_t)rowg * DIM + t * 4;
    ushort4 a0 = *(const ushort4*)(opart + base);
    ushort4 a1 = *(const ushort4*)(opart + (size_t)ROWS * DIM + base);
    ushort4 o;
    o.x = f2bf((bf2f(a0.x) + bf2f(a1.x)) * inv);
    o.y = f2bf((bf2f(a0.y) + bf2f(a1.y)) * inv);
    o.z = f2bf((bf2f(a0.z) + bf2f(a1.z)) * inv);
    o.w = f2bf((bf2f(a0.w) + bf2f(a1.w)) * inv);
    *(ushort4*)(ao + base) = o;
}

extern "C" void kernel_launch(void* const* d_in, const int* in_sizes, int n_in,
                              void* d_out, int out_size, void* d_ws, size_t ws_size,
                              hipStream_t stream) {
    const float* x     = (const float*)d_in[0];
    const float* gamma = (const float*)d_in[1];
    const float* beta  = (const float*)d_in[2];
    const float* Wqk   = (const float*)d_in[3];
    const float* Wv    = (const float*)d_in[4];
    const float* Wout  = (const float*)d_in[5];
    const float* bout  = (const float*)d_in[6];
    float* out = (float*)d_out;

    unsigned short* ws = (unsigned short*)d_ws;
    unsigned short* xn    = ws;                            // 4096*1024      (8 MB)
    unsigned short* Wt_qk = xn + (size_t)ROWS * DIM;       // 2048*1024      (4 MB)
    unsigned short* Wt_v  = Wt_qk + (size_t)2048 * DIM;    // 1024*1024      (2 MB, contiguous)
    unsigned short* Wt_o  = Wt_v + (size_t)DIM * DIM;      // 1024*1024      (2 MB)
    unsigned short* q_h   = Wt_o + (size_t)DIM * DIM;      // 4096*1024      (8 MB)
    unsigned short* k_h   = q_h + (size_t)ROWS * DIM;      // 4096*1024      (8 MB)
    unsigned short* v_t   = k_h + (size_t)ROWS * DIM;      // 4096*1024      (8 MB)
    unsigned short* ao    = v_t + (size_t)ROWS * DIM;      // 4096*1024      (8 MB)
    unsigned short* opart = ao + (size_t)ROWS * DIM;       // 2*4096*1024    (16 MB)
    float*          lpart = (float*)(opart + (size_t)2 * ROWS * DIM);  // 0.5 MB

    ln_kernel<<<ROWS, 256, 0, stream>>>(x, gamma, beta, xn);
    tr_all_kernel<<<dim3(32, 16, 3), 256, 0, stream>>>(Wqk, Wv, Wout, Wt_qk, Wt_v, Wt_o);
    gemm_qkv_kernel<<<dim3(3072 / 128, ROWS / 128), 256, 0, stream>>>(xn, Wt_qk, q_h, k_h, v_t);
    attn_kernel<<<dim3(2 * SEQ / 128, HEADS, BATCH), 256, 0, stream>>>(q_h, k_h, v_t, opart, lpart);
    combine_kernel<<<ROWS, 256, 0, stream>>>(opart, lpart, ao);
    gemm_out_kernel<<<dim3(DIM / 64, ROWS / 128), 256, 0, stream>>>(ao, Wt_o, bout, out);
}